// Round 1
// baseline (1600.378 us; speedup 1.0000x reference)
//
#include <hip/hip_runtime.h>

// Swin window attention, fused per-window kernel.
// B=4096 windows, N=49 tokens, C=384, H=12 heads, hd=32.
// prep kernel: cast qkv_w/proj_w to bf16 in ws, gather bias_table[rel_idx] -> bias_full[h][i][j].
// main kernel: per block = 1 window, 512 threads (8 waves):
//   phase1 QKV GEMM (MFMA bf16, weights staged in LDS), phase2 attention (wave-parallel
//   softmax, O overwrites q tile in LDS), phase3 proj GEMM -> fp32 out.

#define NTOK 49
#define DIM 384
#define HEADS 12
#define LDSTR 392   // padded LDS row stride (bf16 elems) for q/k/v/O: 2-way bank alias only
#define PSTR 56     // per-wave P tile stride
#define WSTR 72     // weight staging stride
#define QKV_ELEMS (1152*384)
#define PROJ_ELEMS (384*384)
#define BIAS_ELEMS (HEADS*NTOK*NTOK)

typedef __attribute__((ext_vector_type(8))) __bf16 bf16x8;
typedef __attribute__((ext_vector_type(4))) float f32x4;

union BF8 { bf16x8 v; unsigned short u[8]; };

__device__ __forceinline__ unsigned short f2bf(float f) {
  union { float f; unsigned u; } x; x.f = f;
  unsigned r = x.u + 0x7fffu + ((x.u >> 16) & 1u);   // RNE
  return (unsigned short)(r >> 16);
}

__device__ __forceinline__ bf16x8 zbf8() {
  BF8 z;
  #pragma unroll
  for (int j = 0; j < 8; ++j) z.u[j] = 0;
  return z.v;
}

__global__ void prep_kernel(const float* __restrict__ qkv_w,
                            const float* __restrict__ proj_w,
                            const float* __restrict__ bias_table,
                            const int* __restrict__ rel_idx,
                            unsigned short* __restrict__ wq,
                            unsigned short* __restrict__ wp,
                            float* __restrict__ bias_full) {
  int i = blockIdx.x * 256 + threadIdx.x;
  if (i < QKV_ELEMS) {
    wq[i] = f2bf(qkv_w[i]);
  } else if (i < QKV_ELEMS + PROJ_ELEMS) {
    int j = i - QKV_ELEMS;
    wp[j] = f2bf(proj_w[j]);
  } else if (i < QKV_ELEMS + PROJ_ELEMS + BIAS_ELEMS) {
    int j = i - QKV_ELEMS - PROJ_ELEMS;
    int h = j / (NTOK * NTOK), rc = j % (NTOK * NTOK);
    bias_full[j] = bias_table[rel_idx[rc] * HEADS + h];
  }
}

// LDS element offsets (unsigned short units)
#define OFF_Q 0
#define OFF_K (NTOK*LDSTR)          // 19208
#define OFF_V (2*NTOK*LDSTR)        // 38416
#define OFF_P (3*NTOK*LDSTR)        // 57624, 8 waves x [16][56]
#define OFF_W (OFF_P + 8*16*PSTR)   // 64792, [128][72]
#define LDS_BYTES ((OFF_W + 128*WSTR) * 2)  // 148016

__global__ __launch_bounds__(512) void fused_win_attn(
    const float* __restrict__ x, const float* __restrict__ mask,
    const float* __restrict__ qkv_b, const float* __restrict__ proj_b,
    const unsigned short* __restrict__ wq, const unsigned short* __restrict__ wp,
    const float* __restrict__ bias_full, float* __restrict__ out) {
  extern __shared__ unsigned short lds[];
  unsigned short* qO  = lds + OFF_Q;   // q, later O (O tile overwrites dead q tile)
  unsigned short* kB  = lds + OFF_K;
  unsigned short* vB  = lds + OFF_V;
  unsigned short* PB  = lds + OFF_P;
  unsigned short* wst = lds + OFF_W;

  const int tid  = threadIdx.x;
  const int wave = tid >> 6, lane = tid & 63;
  const int g = lane >> 4, li = lane & 15;
  const int win = blockIdx.x, wi = win & 63;     // mask index = window % 64
  const int mt = wave >> 1, nh = wave & 1;       // GEMM partition: 4 M-tiles x 2 N-halves
  const int sr = tid >> 2, ss = tid & 3;         // staging row/segment

  // ---- phase 0: load this wave's x A-fragments (fp32 -> bf16), rows >=49 zero ----
  bf16x8 afr[12];
  {
    int row = mt * 16 + li;
    if (row < NTOK) {
      const float* xr = x + ((long)win * NTOK + row) * DIM + g * 8;
      #pragma unroll
      for (int ks = 0; ks < 12; ++ks) {
        float4 f0 = *(const float4*)(xr + ks * 32);
        float4 f1 = *(const float4*)(xr + ks * 32 + 4);
        BF8 t;
        t.u[0] = f2bf(f0.x); t.u[1] = f2bf(f0.y); t.u[2] = f2bf(f0.z); t.u[3] = f2bf(f0.w);
        t.u[4] = f2bf(f1.x); t.u[5] = f2bf(f1.y); t.u[6] = f2bf(f1.z); t.u[7] = f2bf(f1.w);
        afr[ks] = t.v;
      }
    } else {
      bf16x8 z = zbf8();
      #pragma unroll
      for (int ks = 0; ks < 12; ++ks) afr[ks] = z;
    }
  }

  // ---- phase 1: QKV GEMM. 9 chunks of 128 output cols (chunks 0-2=q, 3-5=k, 6-8=v) ----
  for (int c = 0; c < 9; ++c) {
    f32x4 acc[4];
    #pragma unroll
    for (int i = 0; i < 4; ++i) acc[i] = (f32x4){0.f, 0.f, 0.f, 0.f};
    const int colbase = c * 128;
    #pragma unroll
    for (int kst = 0; kst < 6; ++kst) {
      __syncthreads();
      { // stage [128 cols][64 k] bf16 tile of qkv_w
        const unsigned short* src = wq + (colbase + sr) * DIM + kst * 64 + ss * 16;
        *(uint4*)&wst[sr * WSTR + ss * 16]     = *(const uint4*)src;
        *(uint4*)&wst[sr * WSTR + ss * 16 + 8] = *(const uint4*)(src + 8);
      }
      __syncthreads();
      #pragma unroll
      for (int nt = 0; nt < 4; ++nt) {
        #pragma unroll
        for (int k2 = 0; k2 < 2; ++k2) {
          bf16x8 b = *(const bf16x8*)&wst[(nh * 64 + nt * 16 + li) * WSTR + k2 * 32 + g * 8];
          acc[nt] = __builtin_amdgcn_mfma_f32_16x16x32_bf16(afr[kst * 2 + k2], b, acc[nt], 0, 0, 0);
        }
      }
    }
    // C-write into q/k/v LDS (+bias); rows >=49 dropped
    unsigned short* tgt = (c < 3) ? qO : (c < 6) ? kB : vB;
    const int cb = colbase - (c / 3) * DIM;
    #pragma unroll
    for (int nt = 0; nt < 4; ++nt) {
      int colg = colbase + nh * 64 + nt * 16 + li;
      float qb = qkv_b[colg];
      int cc = cb + nh * 64 + nt * 16 + li;
      #pragma unroll
      for (int r4 = 0; r4 < 4; ++r4) {
        int row = mt * 16 + g * 4 + r4;
        if (row < NTOK) tgt[row * LDSTR + cc] = f2bf(acc[nt][r4] + qb);
      }
    }
  }
  __syncthreads();

  // ---- phase 2: attention. 48 tasks (h, mtile), 6 per wave ----
  for (int t6 = 0; t6 < 6; ++t6) {
    const int task = wave + t6 * 8;
    const int h = task >> 2, amt = task & 3;

    // S = Q K^T  (K = hd = 32 -> single MFMA k-step)
    bf16x8 qa;
    {
      int row = amt * 16 + li;
      qa = (row < NTOK) ? *(const bf16x8*)&qO[row * LDSTR + h * 32 + g * 8] : zbf8();
    }
    f32x4 sa[4];
    #pragma unroll
    for (int nt = 0; nt < 4; ++nt) {
      int tok = nt * 16 + li;
      bf16x8 kb = (tok < NTOK) ? *(const bf16x8*)&kB[tok * LDSTR + h * 32 + g * 8] : zbf8();
      f32x4 z4 = (f32x4){0.f, 0.f, 0.f, 0.f};
      sa[nt] = __builtin_amdgcn_mfma_f32_16x16x32_bf16(qa, kb, z4, 0, 0, 0);
    }

    // scale + bias + mask; pad cols -> -1e30
    float sv[4][4];
    #pragma unroll
    for (int nt = 0; nt < 4; ++nt) {
      int col = nt * 16 + li;
      #pragma unroll
      for (int r4 = 0; r4 < 4; ++r4) {
        int row = amt * 16 + g * 4 + r4;
        float val;
        if (col < NTOK) {
          val = sa[nt][r4] * 0.17677669529663687f;
          if (row < NTOK)
            val += bias_full[h * (NTOK * NTOK) + row * NTOK + col]
                 + mask[wi * (NTOK * NTOK) + row * NTOK + col];
        } else {
          val = -1e30f;
        }
        sv[nt][r4] = val;
      }
    }

    // wave-parallel softmax: row r lives in one 16-lane group (xor masks 1,2,4,8)
    #pragma unroll
    for (int r4 = 0; r4 < 4; ++r4) {
      float m = fmaxf(fmaxf(sv[0][r4], sv[1][r4]), fmaxf(sv[2][r4], sv[3][r4]));
      m = fmaxf(m, __shfl_xor(m, 1));
      m = fmaxf(m, __shfl_xor(m, 2));
      m = fmaxf(m, __shfl_xor(m, 4));
      m = fmaxf(m, __shfl_xor(m, 8));
      float s = 0.f;
      #pragma unroll
      for (int nt = 0; nt < 4; ++nt) {
        float e = __expf(sv[nt][r4] - m);
        sv[nt][r4] = e;
        s += e;
      }
      s += __shfl_xor(s, 1); s += __shfl_xor(s, 2);
      s += __shfl_xor(s, 4); s += __shfl_xor(s, 8);
      float inv = 1.f / s;
      #pragma unroll
      for (int nt = 0; nt < 4; ++nt) sv[nt][r4] *= inv;
    }

    // store P (bf16) to per-wave LDS tile [16][56]; cols 49..55 are zeros, 56..63 dropped
    unsigned short* Pw = PB + wave * (16 * PSTR);
    #pragma unroll
    for (int nt = 0; nt < 4; ++nt) {
      int col = nt * 16 + li;
      if (col < PSTR) {
        #pragma unroll
        for (int r4 = 0; r4 < 4; ++r4) Pw[(g * 4 + r4) * PSTR + col] = f2bf(sv[nt][r4]);
      }
    }

    // O = P V  (K = 64 padded tokens -> 2 k-steps; k-group 3 of step 1 is all-pad -> zero frag)
    f32x4 oa[2];
    oa[0] = (f32x4){0.f, 0.f, 0.f, 0.f};
    oa[1] = (f32x4){0.f, 0.f, 0.f, 0.f};
    #pragma unroll
    for (int k2 = 0; k2 < 2; ++k2) {
      bf16x8 pa;
      if (k2 == 1 && g == 3) pa = zbf8();
      else pa = *(const bf16x8*)&Pw[li * PSTR + k2 * 32 + g * 8];
      #pragma unroll
      for (int nt2 = 0; nt2 < 2; ++nt2) {
        BF8 vb;
        #pragma unroll
        for (int j = 0; j < 8; ++j) {
          int tok = k2 * 32 + g * 8 + j;
          vb.u[j] = (tok < NTOK) ? vB[tok * LDSTR + h * 32 + nt2 * 16 + li] : (unsigned short)0;
        }
        oa[nt2] = __builtin_amdgcn_mfma_f32_16x16x32_bf16(pa, vb.v, oa[nt2], 0, 0, 0);
      }
    }

    // write O over the (now dead) q tile of this task
    #pragma unroll
    for (int nt2 = 0; nt2 < 2; ++nt2) {
      int col = h * 32 + nt2 * 16 + li;
      #pragma unroll
      for (int r4 = 0; r4 < 4; ++r4) {
        int row = amt * 16 + g * 4 + r4;
        if (row < NTOK) qO[row * LDSTR + col] = f2bf(oa[nt2][r4]);
      }
    }
  }
  __syncthreads();

  // ---- phase 3: proj GEMM: out = O @ proj_w^T + proj_b ----
  bf16x8 ofr[12];
  {
    int row = mt * 16 + li;
    if (row < NTOK) {
      #pragma unroll
      for (int ks = 0; ks < 12; ++ks)
        ofr[ks] = *(const bf16x8*)&qO[row * LDSTR + ks * 32 + g * 8];
    } else {
      bf16x8 z = zbf8();
      #pragma unroll
      for (int ks = 0; ks < 12; ++ks) ofr[ks] = z;
    }
  }
  for (int pc = 0; pc < 3; ++pc) {
    f32x4 acc[4];
    #pragma unroll
    for (int i = 0; i < 4; ++i) acc[i] = (f32x4){0.f, 0.f, 0.f, 0.f};
    const int colbase = pc * 128;
    #pragma unroll
    for (int kst = 0; kst < 6; ++kst) {
      __syncthreads();
      {
        const unsigned short* src = wp + (colbase + sr) * DIM + kst * 64 + ss * 16;
        *(uint4*)&wst[sr * WSTR + ss * 16]     = *(const uint4*)src;
        *(uint4*)&wst[sr * WSTR + ss * 16 + 8] = *(const uint4*)(src + 8);
      }
      __syncthreads();
      #pragma unroll
      for (int nt = 0; nt < 4; ++nt) {
        #pragma unroll
        for (int k2 = 0; k2 < 2; ++k2) {
          bf16x8 b = *(const bf16x8*)&wst[(nh * 64 + nt * 16 + li) * WSTR + k2 * 32 + g * 8];
          acc[nt] = __builtin_amdgcn_mfma_f32_16x16x32_bf16(ofr[kst * 2 + k2], b, acc[nt], 0, 0, 0);
        }
      }
    }
    #pragma unroll
    for (int nt = 0; nt < 4; ++nt) {
      int col = colbase + nh * 64 + nt * 16 + li;
      float pb = proj_b[col];
      #pragma unroll
      for (int r4 = 0; r4 < 4; ++r4) {
        int row = mt * 16 + g * 4 + r4;
        if (row < NTOK)
          out[((long)win * NTOK + row) * DIM + col] = acc[nt][r4] + pb;
      }
    }
  }
}

extern "C" void kernel_launch(void* const* d_in, const int* in_sizes, int n_in,
                              void* d_out, int out_size, void* d_ws, size_t ws_size,
                              hipStream_t stream) {
  (void)in_sizes; (void)n_in; (void)out_size; (void)ws_size;
  const float* x          = (const float*)d_in[0];
  const float* mask       = (const float*)d_in[1];
  const float* qkv_w      = (const float*)d_in[2];
  const float* qkv_b      = (const float*)d_in[3];
  const float* proj_w     = (const float*)d_in[4];
  const float* proj_b     = (const float*)d_in[5];
  const float* bias_table = (const float*)d_in[6];
  const int*   rel_idx    = (const int*)d_in[7];
  float* out = (float*)d_out;

  unsigned short* wq = (unsigned short*)d_ws;
  unsigned short* wp = wq + QKV_ELEMS;
  float* bias_full = (float*)((char*)d_ws + (size_t)(QKV_ELEMS + PROJ_ELEMS) * 2);

  const int prep_total = QKV_ELEMS + PROJ_ELEMS + BIAS_ELEMS;
  prep_kernel<<<(prep_total + 255) / 256, 256, 0, stream>>>(
      qkv_w, proj_w, bias_table, rel_idx, wq, wp, bias_full);
  fused_win_attn<<<4096, 512, LDS_BYTES, stream>>>(
      x, mask, qkv_b, proj_b, wq, wp, bias_full, out);
}